// Round 9
// baseline (1533.393 us; speedup 1.0000x reference)
//
#include <hip/hip_runtime.h>
#include <cfloat>
#include <math.h>

// VQ-VAE encoder: B=16,S=512,D1=512,D2=256,NH=8,DFF=1024,K=8192,L=3
// Round 9: numerics contract (DO NOT BREAK — validated rounds 2-8):
//  - every GEMM output element: sequential-k FMA chain, kc=384 re-round folds
//  - LN: numpy pairwise-256 order, 1/sqrtf; GELU: f64 erf; VQ dist fl(A-2acc)
//  - attention has rounding freedom (perturbs h at ~1e-9; argmin stable)
// Round-9 changes (split-K removed: ws proven < 64 MiB, doesn't fit):
//  - attn: K/V LDS double-buffer; stage loads issued BEFORE QK compute
//    (hide global latency under FMA); 2 barriers/kc instead of 3
//  - ln: 16 rows/block (grid 512); counts/lossAcc zeroing fused into final LN
//  - vq_partial: grid (64,32) -> 2048 blocks (8/CU available); partV width 32

#define NTOK 8192

// ---------------- numpy pairwise_sum order for 256 contiguous floats --------
__device__ __forceinline__ float np_pairwise256(const float* xs, int lane) {
  float r = 0.f;
  if (lane < 16) {
    const int b = lane >> 3, j = lane & 7;
    const float* p = xs + b * 128 + j;
    r = p[0];
#pragma unroll
    for (int i = 1; i < 16; i++) r += p[i * 8];
  }
  float r0 = __shfl(r, 0), r1 = __shfl(r, 1), r2 = __shfl(r, 2), r3 = __shfl(r, 3);
  float r4 = __shfl(r, 4), r5 = __shfl(r, 5), r6 = __shfl(r, 6), r7 = __shfl(r, 7);
  float s0 = ((r0 + r1) + (r2 + r3)) + ((r4 + r5) + (r6 + r7));
  float q0 = __shfl(r, 8), q1 = __shfl(r, 9), q2 = __shfl(r, 10), q3 = __shfl(r, 11);
  float q4 = __shfl(r, 12), q5 = __shfl(r, 13), q6 = __shfl(r, 14), q7 = __shfl(r, 15);
  float s1 = ((q0 + q1) + (q2 + q3)) + ((q4 + q5) + (q6 + q7));
  return s0 + s1;
}

__device__ __forceinline__ float gelu_np(float x) {
  const float SQRT2F = 1.4142135623730951f;
  float xs = x / SQRT2F;
  float e = (float)erf((double)xs);
  float t = 1.0f + e;
  return (0.5f * x) * t;
}

// ---------------- gemm128 core: 128x128 tile, 8x8 micro, 256 threads --------
// Single-buffered (r4-validated, stays under the 128-VGPR cliff). K <= 384.
__device__ __forceinline__ void gemm128_core(
    const float* __restrict__ A, int lda, const float* __restrict__ Bw,
    const float* __restrict__ bias, float* __restrict__ C,
    int N, int klen, int act, int m0, int n0)
{
  __shared__ float As[16][132];
  __shared__ float Bs[16][132];
  const int tid = threadIdx.x;
  const int tx = tid & 15, ty = tid >> 4;
  const int ar = tid >> 1;
  const int ak = (tid & 1) * 8;
  const int brr = tid >> 5;
  const int bnn = (tid & 31) * 4;
  float accb[8][8] = {};
  const float* Ap = A + (m0 + ar) * lda + ak;
  const float* Bp = Bw + brr * N + n0 + bnn;

  for (int k0 = 0; k0 < klen; k0 += 16) {
    float4 a0 = *(const float4*)(Ap);
    float4 a1 = *(const float4*)(Ap + 4);
    float4 b0 = *(const float4*)(Bp);
    float4 b1 = *(const float4*)(Bp + 8 * N);
    As[ak + 0][ar] = a0.x; As[ak + 1][ar] = a0.y;
    As[ak + 2][ar] = a0.z; As[ak + 3][ar] = a0.w;
    As[ak + 4][ar] = a1.x; As[ak + 5][ar] = a1.y;
    As[ak + 6][ar] = a1.z; As[ak + 7][ar] = a1.w;
    *(float4*)&Bs[brr][bnn] = b0;
    *(float4*)&Bs[brr + 8][bnn] = b1;
    __syncthreads();
#pragma unroll
    for (int kk = 0; kk < 16; kk++) {
      float4 av0 = *(const float4*)&As[kk][ty * 8];
      float4 av1 = *(const float4*)&As[kk][ty * 8 + 4];
      float4 bv0 = *(const float4*)&Bs[kk][tx * 4];        // 2-way: free
      float4 bv1 = *(const float4*)&Bs[kk][64 + tx * 4];   // 2-way: free
      float a[8] = {av0.x, av0.y, av0.z, av0.w, av1.x, av1.y, av1.z, av1.w};
      float b[8] = {bv0.x, bv0.y, bv0.z, bv0.w, bv1.x, bv1.y, bv1.z, bv1.w};
#pragma unroll
      for (int i = 0; i < 8; i++)
#pragma unroll
        for (int j = 0; j < 8; j++) accb[i][j] = fmaf(a[i], b[j], accb[i][j]);
    }
    __syncthreads();
    Ap += 16;
    Bp += 16 * N;
  }
  float4 bbl = make_float4(0.f, 0.f, 0.f, 0.f);
  float4 bbh = make_float4(0.f, 0.f, 0.f, 0.f);
  if (bias) {
    bbl = *(const float4*)&bias[n0 + tx * 4];
    bbh = *(const float4*)&bias[n0 + 64 + tx * 4];
  }
#pragma unroll
  for (int i = 0; i < 8; i++) {
    const int m = m0 + ty * 8 + i;
    float4 lo, hi;
    lo.x = accb[i][0] + bbl.x; lo.y = accb[i][1] + bbl.y;
    lo.z = accb[i][2] + bbl.z; lo.w = accb[i][3] + bbl.w;
    hi.x = accb[i][4] + bbh.x; hi.y = accb[i][5] + bbh.y;
    hi.z = accb[i][6] + bbh.z; hi.w = accb[i][7] + bbh.w;
    if (act == 1) {
      lo.x = gelu_np(lo.x); lo.y = gelu_np(lo.y);
      lo.z = gelu_np(lo.z); lo.w = gelu_np(lo.w);
      hi.x = gelu_np(hi.x); hi.y = gelu_np(hi.y);
      hi.z = gelu_np(hi.z); hi.w = gelu_np(hi.w);
    }
    *(float4*)&C[m * N + n0 + tx * 4] = lo;
    *(float4*)&C[m * N + n0 + 64 + tx * 4] = hi;
  }
}

__global__ __launch_bounds__(256) void qkv_kernel(
    const float* __restrict__ h,
    const float* __restrict__ wq, const float* __restrict__ bq,
    const float* __restrict__ wk, const float* __restrict__ bk,
    const float* __restrict__ wv, const float* __restrict__ bv,
    float* __restrict__ Q, float* __restrict__ K, float* __restrict__ V)
{
  const int sel = blockIdx.y >> 1;
  const int n0 = (blockIdx.y & 1) * 128;
  const float* W = (sel == 0) ? wq : (sel == 1) ? wk : wv;
  const float* bb = (sel == 0) ? bq : (sel == 1) ? bk : bv;
  float* C = (sel == 0) ? Q : (sel == 1) ? K : V;
  gemm128_core(h, 256, W, bb, C, 256, 256, 0, blockIdx.x * 128, n0);
}

__global__ __launch_bounds__(256) void gemm128_kernel(
    const float* __restrict__ A, const float* __restrict__ B,
    const float* __restrict__ bias, float* __restrict__ C,
    int N, int K, int act)
{
  gemm128_core(A, K, B, bias, C, N, K, act, blockIdx.x * 128, blockIdx.y * 128);
}

// ---------------- GEMM 64x64 tile, 4x4 micro, double-buffered LDS -----------
__global__ __launch_bounds__(256) void gemm64_kernel(
    const float* __restrict__ A, const float* __restrict__ B,
    const float* __restrict__ bias, float* __restrict__ C,
    int M, int N, int K, int act)
{
  __shared__ float As[2][16][68];
  __shared__ float Bs[2][16][68];
  const int tid = threadIdx.x;
  const int tx = tid & 15, ty = tid >> 4;
  const int m0 = blockIdx.x * 64, n0 = blockIdx.y * 64;
  const int ar = tid >> 2;
  const int ak = (tid & 3) * 4;
  const int br = tid >> 4;
  const int bn = (tid & 15) * 4;
  const float* Ap = A + (m0 + ar) * K + ak;
  const float* Bp = B + br * N + n0 + bn;
  float acc[4][4] = {};
  float accb[4][4] = {};
  const int nk = K >> 4;

  float4 aR = *(const float4*)(Ap);
  float4 bR = *(const float4*)(Bp);
  As[0][ak + 0][ar] = aR.x; As[0][ak + 1][ar] = aR.y;
  As[0][ak + 2][ar] = aR.z; As[0][ak + 3][ar] = aR.w;
  *(float4*)&Bs[0][br][bn] = bR;

  for (int t = 0; t < nk; t++) {
    const int p = t & 1;
    __syncthreads();
    if (t + 1 < nk) {
      aR = *(const float4*)(Ap + (t + 1) * 16);
      bR = *(const float4*)(Bp + (t + 1) * 16 * N);
    }
#pragma unroll
    for (int kk = 0; kk < 16; kk++) {
      float4 av = *(const float4*)&As[p][kk][ty * 4];
      float4 bv = *(const float4*)&Bs[p][kk][tx * 4];
      float a[4] = {av.x, av.y, av.z, av.w};
      float b[4] = {bv.x, bv.y, bv.z, bv.w};
#pragma unroll
      for (int i = 0; i < 4; i++)
#pragma unroll
        for (int j = 0; j < 4; j++) accb[i][j] = fmaf(a[i], b[j], accb[i][j]);
    }
    if (((((t + 1) << 4) % 384) == 0) || (t + 1 == nk)) {
#pragma unroll
      for (int i = 0; i < 4; i++)
#pragma unroll
        for (int j = 0; j < 4; j++) { acc[i][j] += accb[i][j]; accb[i][j] = 0.f; }
    }
    if (t + 1 < nk) {
      const int q = p ^ 1;
      As[q][ak + 0][ar] = aR.x; As[q][ak + 1][ar] = aR.y;
      As[q][ak + 2][ar] = aR.z; As[q][ak + 3][ar] = aR.w;
      *(float4*)&Bs[q][br][bn] = bR;
    }
  }
  float4 bb4 = make_float4(0.f, 0.f, 0.f, 0.f);
  if (bias) bb4 = *(const float4*)&bias[n0 + tx * 4];
#pragma unroll
  for (int i = 0; i < 4; i++) {
    float4 o;
    o.x = acc[i][0] + bb4.x;
    o.y = acc[i][1] + bb4.y;
    o.z = acc[i][2] + bb4.z;
    o.w = acc[i][3] + bb4.w;
    if (act == 1) {
      o.x = gelu_np(o.x); o.y = gelu_np(o.y);
      o.z = gelu_np(o.z); o.w = gelu_np(o.w);
    }
    *(float4*)&C[(m0 + ty * 4 + i) * N + n0 + tx * 4] = o;
  }
}

// ---------------- flash-tile attention: 64q x 32k, K/V double-buffered ------
// 2 barriers/kc. Stage loads for kc+1 issue BEFORE QK compute of kc so the
// global latency hides under ~1300 cyc of FMA. Buffer parity: PV(kc-1) reads
// p^1 strictly before top-barrier(kc); stage writes p^1 strictly after.
__global__ __launch_bounds__(256) void attn_kernel(
    const float* __restrict__ Q, const float* __restrict__ Kb,
    const float* __restrict__ Vb, float* __restrict__ ctx)
{
  __shared__ float Qs[64][36];
  __shared__ float Ks[2][32][36];
  __shared__ float Vs[2][32][36];
  __shared__ float Ps[64][33];
  __shared__ float l_lds[64];
  const int tid = threadIdx.x;
  const int b = blockIdx.x >> 3, h = blockIdx.x & 7;
  const int q0 = blockIdx.y * 64;
  const int base = (b * 512) * 256 + h * 32;
  const float scale = 0.17677669529663687f;  // fl32(1/sqrt(32))

  {  // stage Q tile (64 x 32)
    int i0 = tid * 2;
    int r = i0 >> 3, c = i0 & 7;
    *(float4*)&Qs[r][c * 4] = *(const float4*)(Q + base + (q0 + r) * 256 + c * 4);
    int i1 = i0 + 1;
    r = i1 >> 3; c = i1 & 7;
    *(float4*)&Qs[r][c * 4] = *(const float4*)(Q + base + (q0 + r) * 256 + c * 4);
  }
  if (tid < 64) l_lds[tid] = 0.f;

  const int sr = tid >> 3, sc = tid & 7;     // staging: row 0..31, col-quad 0..7
  {  // prologue: stage chunk 0 into buffer 0
    float4 k0v = *(const float4*)(Kb + base + sr * 256 + sc * 4);
    float4 v0v = *(const float4*)(Vb + base + sr * 256 + sc * 4);
    *(float4*)&Ks[0][sr][sc * 4] = k0v;
    *(float4*)&Vs[0][sr][sc * 4] = v0v;
  }

  const int tx = tid & 15, ty = tid >> 4;    // QK: 4q x {tx, tx+16} keys
  const int tx2 = tid & 7, ty2 = tid >> 3;   // PV: 2q x 4d
  float acc[2][4] = {};

  for (int kc = 0; kc < 16; kc++) {
    const int p = kc & 1;
    __syncthreads();  // Ks/Vs[p] + (kc=0: Q,l) visible; Ps consumed by PV(kc-1)
    float4 kst, vst;
    if (kc < 15) {  // issue loads early: latency hides under QK FMA
      int tok = (kc + 1) * 32 + sr;
      kst = *(const float4*)(Kb + base + tok * 256 + sc * 4);
      vst = *(const float4*)(Vb + base + tok * 256 + sc * 4);
    }
    // QK^T from Ks[p]
    float s0[4] = {}, s1[4] = {};
#pragma unroll
    for (int d = 0; d < 32; d += 4) {
      float4 k0 = *(const float4*)&Ks[p][tx][d];
      float4 k1 = *(const float4*)&Ks[p][tx + 16][d];
#pragma unroll
      for (int i = 0; i < 4; i++) {
        float4 qv = *(const float4*)&Qs[ty * 4 + i][d];
        s0[i] = fmaf(qv.w, k0.w, fmaf(qv.z, k0.z, fmaf(qv.y, k0.y, fmaf(qv.x, k0.x, s0[i]))));
        s1[i] = fmaf(qv.w, k1.w, fmaf(qv.z, k1.z, fmaf(qv.y, k1.y, fmaf(qv.x, k1.x, s1[i]))));
      }
    }
    if (kc < 15) {  // write staged chunk to the idle buffer
      *(float4*)&Ks[p ^ 1][sr][sc * 4] = kst;
      *(float4*)&Vs[p ^ 1][sr][sc * 4] = vst;
    }
    float rs[4];
#pragma unroll
    for (int i = 0; i < 4; i++) {
      float p0 = expf(s0[i] * scale);
      float p1 = expf(s1[i] * scale);
      Ps[ty * 4 + i][tx] = p0;
      Ps[ty * 4 + i][tx + 16] = p1;
      rs[i] = p0 + p1;
    }
#pragma unroll
    for (int off = 1; off < 16; off <<= 1)
#pragma unroll
      for (int i = 0; i < 4; i++) rs[i] += __shfl_xor(rs[i], off);
    if (tx == 0) {
#pragma unroll
      for (int i = 0; i < 4; i++) l_lds[ty * 4 + i] += rs[i];
    }
    __syncthreads();  // Ps ready; staged LDS writes drained
    // PV from Vs[p]
#pragma unroll 4
    for (int k = 0; k < 32; k++) {
      float4 vv = *(const float4*)&Vs[p][k][tx2 * 4];
      float pa = Ps[ty2 * 2][k];
      float pb = Ps[ty2 * 2 + 1][k];
      acc[0][0] = fmaf(pa, vv.x, acc[0][0]);
      acc[0][1] = fmaf(pa, vv.y, acc[0][1]);
      acc[0][2] = fmaf(pa, vv.z, acc[0][2]);
      acc[0][3] = fmaf(pa, vv.w, acc[0][3]);
      acc[1][0] = fmaf(pb, vv.x, acc[1][0]);
      acc[1][1] = fmaf(pb, vv.y, acc[1][1]);
      acc[1][2] = fmaf(pb, vv.z, acc[1][2]);
      acc[1][3] = fmaf(pb, vv.w, acc[1][3]);
    }
  }
  __syncthreads();
#pragma unroll
  for (int i = 0; i < 2; i++) {
    float inv = 1.f / l_lds[ty2 * 2 + i];
    float4 o;
    o.x = acc[i][0] * inv; o.y = acc[i][1] * inv;
    o.z = acc[i][2] * inv; o.w = acc[i][3] * inv;
    *(float4*)(ctx + base + (q0 + ty2 * 2 + i) * 256 + tx2 * 4) = o;
  }
}

// ------- fused residual + LayerNorm, 16 rows/block (+Atok, +counts-zero) ----
__global__ __launch_bounds__(256) void ln_kernel(
    const float* __restrict__ X, const float* __restrict__ R,
    const float* __restrict__ g, const float* __restrict__ bt,
    float* __restrict__ Y, int hasR, float* __restrict__ Atok,
    int* __restrict__ counts, float* __restrict__ lossAcc)
{
  __shared__ float rows[4][256];
  const int w = threadIdx.x >> 6, lane = threadIdx.x & 63;
  float4 gv = *(const float4*)(g + lane * 4);
  float4 bv = *(const float4*)(bt + lane * 4);
  if (counts && blockIdx.x < 32) {
    int i = blockIdx.x * 256 + threadIdx.x;
    counts[i] = 0;
    if (i == 0) lossAcc[0] = 0.f;
  }
#pragma unroll 1
  for (int rr = 0; rr < 4; rr++) {
    const int row = blockIdx.x * 16 + w * 4 + rr;
    float4 xv = *(const float4*)(X + row * 256 + lane * 4);
    if (hasR) {
      float4 rv = *(const float4*)(R + row * 256 + lane * 4);
      xv.x += rv.x; xv.y += rv.y; xv.z += rv.z; xv.w += rv.w;
    }
    *(float4*)&rows[w][lane * 4] = xv;
    __syncthreads();
    float sum = np_pairwise256(rows[w], lane);
    float mean = sum * (1.0f / 256.0f);
    float dx = xv.x - mean, dy = xv.y - mean, dz = xv.z - mean, dw = xv.w - mean;
    __syncthreads();
    float4 sq; sq.x = dx * dx; sq.y = dy * dy; sq.z = dz * dz; sq.w = dw * dw;
    *(float4*)&rows[w][lane * 4] = sq;
    __syncthreads();
    float vsum = np_pairwise256(rows[w], lane);
    float var = vsum * (1.0f / 256.0f);
    float inv = 1.0f / sqrtf(var + 1e-5f);
    float4 o;
    o.x = ((dx * inv) * gv.x) + bv.x;
    o.y = ((dy * inv) * gv.y) + bv.y;
    o.z = ((dz * inv) * gv.z) + bv.z;
    o.w = ((dw * inv) * gv.w) + bv.w;
    *(float4*)(Y + row * 256 + lane * 4) = o;
    if (Atok) {
      float4 s2; s2.x = o.x * o.x; s2.y = o.y * o.y;
      s2.z = o.z * o.z; s2.w = o.w * o.w;
      __syncthreads();
      *(float4*)&rows[w][lane * 4] = s2;
      __syncthreads();
      float asum = np_pairwise256(rows[w], lane);
      if (lane == 0) Atok[row] = asum;
    }
    __syncthreads();  // rows re-used next rr
  }
}

// ---------------- VQ pass 1: 128 tok x 256 codes/block, 8x8 micro -----------
// grid (64,32) = 2048 blocks (8/CU available). r6-validated inner structure.
__global__ __launch_bounds__(256) void vq_partial_kernel(
    const float* __restrict__ H, const float* __restrict__ CB,
    const float* __restrict__ Atok, float* __restrict__ partV,
    int* __restrict__ partI)
{
  __shared__ float As[16][132];
  __shared__ float Bs[16][132];
  const int tid = threadIdx.x;
  const int tx = tid & 15, ty = tid >> 4;
  const int m0 = blockIdx.x * 128;
  const int cg0 = blockIdx.y * 256;
  const int ar = tid >> 1;
  const int ak = (tid & 1) * 8;
  float At[8];
#pragma unroll
  for (int i = 0; i < 8; i++) At[i] = Atok[m0 + ty * 8 + i];
  float bestV[8];
  int bestI[8];
#pragma unroll
  for (int i = 0; i < 8; i++) { bestV[i] = FLT_MAX; bestI[i] = 0; }

  for (int ct = 0; ct < 2; ct++) {
    const int c0 = cg0 + ct * 128;
    float acc[8][8] = {};
    const float* Ap = H + (m0 + ar) * 256 + ak;
    const float* Bp = CB + (c0 + ar) * 256 + ak;
    for (int k0 = 0; k0 < 256; k0 += 16) {
      float4 a0 = *(const float4*)(Ap);
      float4 a1 = *(const float4*)(Ap + 4);
      float4 c0v = *(const float4*)(Bp);
      float4 c1v = *(const float4*)(Bp + 4);
      As[ak + 0][ar] = a0.x; As[ak + 1][ar] = a0.y;
      As[ak + 2][ar] = a0.z; As[ak + 3][ar] = a0.w;
      As[ak + 4][ar] = a1.x; As[ak + 5][ar] = a1.y;
      As[ak + 6][ar] = a1.z; As[ak + 7][ar] = a1.w;
      Bs[ak + 0][ar] = c0v.x; Bs[ak + 1][ar] = c0v.y;
      Bs[ak + 2][ar] = c0v.z; Bs[ak + 3][ar] = c0v.w;
      Bs[ak + 4][ar] = c1v.x; Bs[ak + 5][ar] = c1v.y;
      Bs[ak + 6][ar] = c1v.z; Bs[ak + 7][ar] = c1v.w;
      __syncthreads();
#pragma unroll
      for (int kk = 0; kk < 16; kk++) {
        float4 av0 = *(const float4*)&As[kk][ty * 8];
        float4 av1 = *(const float4*)&As[kk][ty * 8 + 4];
        float4 bv0 = *(const float4*)&Bs[kk][tx * 4];       // 2-way: free
        float4 bv1 = *(const float4*)&Bs[kk][64 + tx * 4];  // 2-way: free
        float a[8] = {av0.x, av0.y, av0.z, av0.w, av1.x, av1.y, av1.z, av1.w};
        float b[8] = {bv0.x, bv0.y, bv0.z, bv0.w, bv1.x, bv1.y, bv1.z, bv1.w};
#pragma unroll
        for (int i = 0; i < 8; i++)
#pragma unroll
          for (int j = 0; j < 8; j++) acc[i][j] = fmaf(a[i], b[j], acc[i][j]);
      }
      __syncthreads();
      Ap += 16;
      Bp += 16;
    }
#pragma unroll
    for (int i = 0; i < 8; i++) {
#pragma unroll
      for (int j = 0; j < 8; j++) {
        int code = c0 + ((j < 4) ? (tx * 4 + j) : (64 + tx * 4 + (j - 4)));
        float v = At[i] - 2.0f * acc[i][j];  // fl(A - 2*acc), single rounding
        if (v < bestV[i]) { bestV[i] = v; bestI[i] = code; }
      }
    }
  }
#pragma unroll
  for (int i = 0; i < 8; i++) {
    float v = bestV[i];
    int ii = bestI[i];
#pragma unroll
    for (int off = 1; off < 16; off <<= 1) {
      float ov = __shfl_xor(v, off);
      int oi = __shfl_xor(ii, off);
      if (ov < v || (ov == v && oi < ii)) { v = ov; ii = oi; }
    }
    if (tx == 0) {
      int token = m0 + ty * 8 + i;
      partV[token * 32 + blockIdx.y] = v;
      partI[token * 32 + blockIdx.y] = ii;
    }
  }
}

// ---------------- VQ pass 2: final argmin (32 partials), gather, loss -------
__global__ __launch_bounds__(256) void vq_final_kernel(
    const float* __restrict__ partV, const int* __restrict__ partI,
    const float* __restrict__ HN, const float* __restrict__ CB,
    float* __restrict__ outQuant, float* __restrict__ outIdxF,
    int* __restrict__ idxInt, int* __restrict__ counts,
    float* __restrict__ lossAcc)
{
  const int w = threadIdx.x >> 6, lane = threadIdx.x & 63;
  const int t = blockIdx.x * 4 + w;
  float v = (lane < 32) ? partV[t * 32 + lane] : FLT_MAX;
  int i = (lane < 32) ? partI[t * 32 + lane] : 0x7fffffff;
#pragma unroll
  for (int off = 16; off; off >>= 1) {
    float ov = __shfl_xor(v, off);
    int oi = __shfl_xor(i, off);
    if (ov < v || (ov == v && oi < i)) { v = ov; i = oi; }
  }
  int idx = __shfl(i, 0);
  const float* c = CB + idx * 256;
  const float* hh = HN + t * 256;
  float4 cv = *(const float4*)(c + lane * 4);
  float4 hv = *(const float4*)(hh + lane * 4);
  *(float4*)(outQuant + t * 256 + lane * 4) = cv;
  float ex = cv.x - hv.x, ey = cv.y - hv.y, ez = cv.z - hv.z, ew = cv.w - hv.w;
  float se = ex * ex + ey * ey + ez * ez + ew * ew;
#pragma unroll
  for (int off = 32; off; off >>= 1) se += __shfl_xor(se, off);
  if (lane == 0) {
    outIdxF[t] = (float)idx;
    idxInt[t] = idx;
    atomicAdd(&counts[idx], 1);
    atomicAdd(lossAcc, se);
  }
}

// ---------------- VQ stats: loss finalize + perplexity ----------------------
__global__ __launch_bounds__(256) void vq_stats_kernel(
    const int* __restrict__ counts, const float* __restrict__ lossAcc,
    float* __restrict__ out)
{
  float ent = 0.f;
  for (int k = threadIdx.x; k < 8192; k += 256) {
    float p = (float)counts[k] * (1.0f / 8192.0f);
    ent += p * logf(p + 1e-10f);
  }
#pragma unroll
  for (int off = 32; off; off >>= 1) ent += __shfl_xor(ent, off);
  __shared__ float ws4[4];
  const int w = threadIdx.x >> 6, lane = threadIdx.x & 63;
  if (lane == 0) ws4[w] = ent;
  __syncthreads();
  if (threadIdx.x == 0) {
    float e = ws4[0] + ws4[1] + ws4[2] + ws4[3];
    out[2097152] = 1.25f * lossAcc[0] * (1.0f / 2097152.0f);
    out[2097153] = expf(-e);
  }
}

extern "C" void kernel_launch(void* const* d_in, const int* in_sizes, int n_in,
                              void* d_out, int out_size, void* d_ws, size_t ws_size,
                              hipStream_t stream) {
  const float* x = (const float*)d_in[0];
  const float* w_in = (const float*)d_in[1];
  const float* b_in = (const float*)d_in[2];
  const float* wq = (const float*)d_in[3];
  const float* bq = (const float*)d_in[4];
  const float* wk = (const float*)d_in[5];
  const float* bk = (const float*)d_in[6];
  const float* wv = (const float*)d_in[7];
  const float* bv = (const float*)d_in[8];
  const float* wo = (const float*)d_in[9];
  const float* bo = (const float*)d_in[10];
  const float* ln1g = (const float*)d_in[11];
  const float* ln1b = (const float*)d_in[12];
  const float* ln2g = (const float*)d_in[13];
  const float* ln2b = (const float*)d_in[14];
  const float* ff1w = (const float*)d_in[15];
  const float* ff1b = (const float*)d_in[16];
  const float* ff2w = (const float*)d_in[17];
  const float* ff2b = (const float*)d_in[18];
  const float* preg = (const float*)d_in[19];
  const float* preb = (const float*)d_in[20];
  const float* cb = (const float*)d_in[21];
  float* out = (float*)d_out;

  if (ws_size < (51ull << 20)) return;
  char* ws = (char*)d_ws;
  float* h = (float*)(ws + 0);                  // 0-8MB, live whole transformer
  float* Qb = (float*)(ws + (8ull << 20));      // 8-16MB: Qb -> Ob -> F2 -> HN
  float* Kb2 = (float*)(ws + (16ull << 20));    // 16-24MB (dead after attn)
  float* Vb = (float*)(ws + (24ull << 20));     // 24-32MB (dead after attn)
  float* Cx = (float*)(ws + (32ull << 20));     // 32-40MB (dead after outproj)
  float* Ob = Qb;
  float* F1 = Kb2;                              // 16-48MB [8192,1024]
  float* F2 = Qb;
  float* HN = Qb;
  // smalls at 48MB+ (~50.7MB end, under the 51MB floor)
  char* smallbase = ws + (48ull << 20);
  float* Atok = (float*)(smallbase);                                   // 32KB
  float* partV = (float*)(smallbase + (512ull << 10));                 // 1MB
  int* partI = (int*)(smallbase + (512ull << 10) + (1ull << 20));      // 1MB
  int* idxInt = (int*)(smallbase + (512ull << 10) + (2ull << 20));     // 32KB
  int* counts = (int*)(smallbase + (512ull << 10) + (2ull << 20) + (64ull << 10));
  float* lossAcc = (float*)(smallbase + (512ull << 10) + (2ull << 20) + (128ull << 10));

  // h = x @ w_in + b_in   [8192,512]x[512,256]
  gemm64_kernel<<<dim3(128, 4), 256, 0, stream>>>(x, w_in, b_in, h, NTOK, 256, 512, 0);

  for (int i = 0; i < 3; i++) {
    qkv_kernel<<<dim3(64, 6), 256, 0, stream>>>(
        h, wq + i * 65536, bq + i * 256, wk + i * 65536, bk + i * 256,
        wv + i * 65536, bv + i * 256, Qb, Kb2, Vb);
    attn_kernel<<<dim3(128, 8), 256, 0, stream>>>(Qb, Kb2, Vb, Cx);
    gemm64_kernel<<<dim3(128, 4), 256, 0, stream>>>(Cx, wo + i * 65536, bo + i * 256, Ob, NTOK, 256, 256, 0);
    ln_kernel<<<512, 256, 0, stream>>>(h, Ob, ln1g + i * 256, ln1b + i * 256, h, 1, nullptr, nullptr, nullptr);
    gemm128_kernel<<<dim3(64, 8), 256, 0, stream>>>(h, ff1w + i * 262144, ff1b + i * 1024, F1, 1024, 256, 1);
    gemm64_kernel<<<dim3(128, 4), 256, 0, stream>>>(F1, ff2w + i * 262144, ff2b + i * 256, F2, NTOK, 256, 1024, 0);
    ln_kernel<<<512, 256, 0, stream>>>(h, F2, ln2g + i * 256, ln2b + i * 256, h, 1, nullptr, nullptr, nullptr);
  }
  // final LN + Atok + counts/lossAcc zeroing (all consumed after this point)
  ln_kernel<<<512, 256, 0, stream>>>(h, nullptr, preg, preb, HN, 0, Atok, counts, lossAcc);

  vq_partial_kernel<<<dim3(64, 32), 256, 0, stream>>>(HN, cb, Atok, partV, partI);
  vq_final_kernel<<<2048, 256, 0, stream>>>(partV, partI, HN, cb,
                                            out, out + 2097154, idxInt, counts, lossAcc);
  vq_stats_kernel<<<1, 256, 0, stream>>>(counts, lossAcc, out);
}

// Round 10
// 1479.389 us; speedup vs baseline: 1.0365x; 1.0365x over previous
//
#include <hip/hip_runtime.h>
#include <cfloat>
#include <math.h>

// VQ-VAE encoder: B=16,S=512,D1=512,D2=256,NH=8,DFF=1024,K=8192,L=3
// Round 10: numerics contract (DO NOT BREAK — validated rounds 2-9):
//  - every GEMM output element: sequential-k FMA chain, kc=384 re-round folds
//  - LN: numpy pairwise-256 order, 1/sqrtf; GELU: f64 erf; VQ dist fl(A-2acc)
//  - attention has rounding freedom (perturbs h at ~1e-9; argmin stable)
// Round-10 = recombination of best validated pieces (no new structure):
//  - attn: r6/r8 single-buffered flash-tile (r9's dbuf cut occupancy 6->4)
//  - ln: r8 4-rows/block grid-2048 (r9's 16-row loop serialized on barriers)
//  - vq_partial: r9's (64,32) grid, 256 codes/block (validated -13us,
//    occ 26->29.5%, VALUBusy 75%); partV width 32, vq_final 32-way reduce
//  - occupancy-fragility lesson (r5/r7/r9): do NOT trade LDS/VGPR/grid for
//    pipelining in these kernels

#define NTOK 8192

// ---------------- numpy pairwise_sum order for 256 contiguous floats --------
__device__ __forceinline__ float np_pairwise256(const float* xs, int lane) {
  float r = 0.f;
  if (lane < 16) {
    const int b = lane >> 3, j = lane & 7;
    const float* p = xs + b * 128 + j;
    r = p[0];
#pragma unroll
    for (int i = 1; i < 16; i++) r += p[i * 8];
  }
  float r0 = __shfl(r, 0), r1 = __shfl(r, 1), r2 = __shfl(r, 2), r3 = __shfl(r, 3);
  float r4 = __shfl(r, 4), r5 = __shfl(r, 5), r6 = __shfl(r, 6), r7 = __shfl(r, 7);
  float s0 = ((r0 + r1) + (r2 + r3)) + ((r4 + r5) + (r6 + r7));
  float q0 = __shfl(r, 8), q1 = __shfl(r, 9), q2 = __shfl(r, 10), q3 = __shfl(r, 11);
  float q4 = __shfl(r, 12), q5 = __shfl(r, 13), q6 = __shfl(r, 14), q7 = __shfl(r, 15);
  float s1 = ((q0 + q1) + (q2 + q3)) + ((q4 + q5) + (q6 + q7));
  return s0 + s1;
}

__device__ __forceinline__ float gelu_np(float x) {
  const float SQRT2F = 1.4142135623730951f;
  float xs = x / SQRT2F;
  float e = (float)erf((double)xs);
  float t = 1.0f + e;
  return (0.5f * x) * t;
}

// ---------------- gemm128 core: 128x128 tile, 8x8 micro, 256 threads --------
// Single-buffered (r4-validated, stays under the 128-VGPR cliff). K <= 384.
__device__ __forceinline__ void gemm128_core(
    const float* __restrict__ A, int lda, const float* __restrict__ Bw,
    const float* __restrict__ bias, float* __restrict__ C,
    int N, int klen, int act, int m0, int n0)
{
  __shared__ float As[16][132];
  __shared__ float Bs[16][132];
  const int tid = threadIdx.x;
  const int tx = tid & 15, ty = tid >> 4;
  const int ar = tid >> 1;
  const int ak = (tid & 1) * 8;
  const int brr = tid >> 5;
  const int bnn = (tid & 31) * 4;
  float accb[8][8] = {};
  const float* Ap = A + (m0 + ar) * lda + ak;
  const float* Bp = Bw + brr * N + n0 + bnn;

  for (int k0 = 0; k0 < klen; k0 += 16) {
    float4 a0 = *(const float4*)(Ap);
    float4 a1 = *(const float4*)(Ap + 4);
    float4 b0 = *(const float4*)(Bp);
    float4 b1 = *(const float4*)(Bp + 8 * N);
    As[ak + 0][ar] = a0.x; As[ak + 1][ar] = a0.y;
    As[ak + 2][ar] = a0.z; As[ak + 3][ar] = a0.w;
    As[ak + 4][ar] = a1.x; As[ak + 5][ar] = a1.y;
    As[ak + 6][ar] = a1.z; As[ak + 7][ar] = a1.w;
    *(float4*)&Bs[brr][bnn] = b0;
    *(float4*)&Bs[brr + 8][bnn] = b1;
    __syncthreads();
#pragma unroll
    for (int kk = 0; kk < 16; kk++) {
      float4 av0 = *(const float4*)&As[kk][ty * 8];
      float4 av1 = *(const float4*)&As[kk][ty * 8 + 4];
      float4 bv0 = *(const float4*)&Bs[kk][tx * 4];        // 2-way: free
      float4 bv1 = *(const float4*)&Bs[kk][64 + tx * 4];   // 2-way: free
      float a[8] = {av0.x, av0.y, av0.z, av0.w, av1.x, av1.y, av1.z, av1.w};
      float b[8] = {bv0.x, bv0.y, bv0.z, bv0.w, bv1.x, bv1.y, bv1.z, bv1.w};
#pragma unroll
      for (int i = 0; i < 8; i++)
#pragma unroll
        for (int j = 0; j < 8; j++) accb[i][j] = fmaf(a[i], b[j], accb[i][j]);
    }
    __syncthreads();
    Ap += 16;
    Bp += 16 * N;
  }
  float4 bbl = make_float4(0.f, 0.f, 0.f, 0.f);
  float4 bbh = make_float4(0.f, 0.f, 0.f, 0.f);
  if (bias) {
    bbl = *(const float4*)&bias[n0 + tx * 4];
    bbh = *(const float4*)&bias[n0 + 64 + tx * 4];
  }
#pragma unroll
  for (int i = 0; i < 8; i++) {
    const int m = m0 + ty * 8 + i;
    float4 lo, hi;
    lo.x = accb[i][0] + bbl.x; lo.y = accb[i][1] + bbl.y;
    lo.z = accb[i][2] + bbl.z; lo.w = accb[i][3] + bbl.w;
    hi.x = accb[i][4] + bbh.x; hi.y = accb[i][5] + bbh.y;
    hi.z = accb[i][6] + bbh.z; hi.w = accb[i][7] + bbh.w;
    if (act == 1) {
      lo.x = gelu_np(lo.x); lo.y = gelu_np(lo.y);
      lo.z = gelu_np(lo.z); lo.w = gelu_np(lo.w);
      hi.x = gelu_np(hi.x); hi.y = gelu_np(hi.y);
      hi.z = gelu_np(hi.z); hi.w = gelu_np(hi.w);
    }
    *(float4*)&C[m * N + n0 + tx * 4] = lo;
    *(float4*)&C[m * N + n0 + 64 + tx * 4] = hi;
  }
}

__global__ __launch_bounds__(256) void qkv_kernel(
    const float* __restrict__ h,
    const float* __restrict__ wq, const float* __restrict__ bq,
    const float* __restrict__ wk, const float* __restrict__ bk,
    const float* __restrict__ wv, const float* __restrict__ bv,
    float* __restrict__ Q, float* __restrict__ K, float* __restrict__ V)
{
  const int sel = blockIdx.y >> 1;
  const int n0 = (blockIdx.y & 1) * 128;
  const float* W = (sel == 0) ? wq : (sel == 1) ? wk : wv;
  const float* bb = (sel == 0) ? bq : (sel == 1) ? bk : bv;
  float* C = (sel == 0) ? Q : (sel == 1) ? K : V;
  gemm128_core(h, 256, W, bb, C, 256, 256, 0, blockIdx.x * 128, n0);
}

__global__ __launch_bounds__(256) void gemm128_kernel(
    const float* __restrict__ A, const float* __restrict__ B,
    const float* __restrict__ bias, float* __restrict__ C,
    int N, int K, int act)
{
  gemm128_core(A, K, B, bias, C, N, K, act, blockIdx.x * 128, blockIdx.y * 128);
}

// ---------------- GEMM 64x64 tile, 4x4 micro, double-buffered LDS -----------
__global__ __launch_bounds__(256) void gemm64_kernel(
    const float* __restrict__ A, const float* __restrict__ B,
    const float* __restrict__ bias, float* __restrict__ C,
    int M, int N, int K, int act)
{
  __shared__ float As[2][16][68];
  __shared__ float Bs[2][16][68];
  const int tid = threadIdx.x;
  const int tx = tid & 15, ty = tid >> 4;
  const int m0 = blockIdx.x * 64, n0 = blockIdx.y * 64;
  const int ar = tid >> 2;
  const int ak = (tid & 3) * 4;
  const int br = tid >> 4;
  const int bn = (tid & 15) * 4;
  const float* Ap = A + (m0 + ar) * K + ak;
  const float* Bp = B + br * N + n0 + bn;
  float acc[4][4] = {};
  float accb[4][4] = {};
  const int nk = K >> 4;

  float4 aR = *(const float4*)(Ap);
  float4 bR = *(const float4*)(Bp);
  As[0][ak + 0][ar] = aR.x; As[0][ak + 1][ar] = aR.y;
  As[0][ak + 2][ar] = aR.z; As[0][ak + 3][ar] = aR.w;
  *(float4*)&Bs[0][br][bn] = bR;

  for (int t = 0; t < nk; t++) {
    const int p = t & 1;
    __syncthreads();
    if (t + 1 < nk) {
      aR = *(const float4*)(Ap + (t + 1) * 16);
      bR = *(const float4*)(Bp + (t + 1) * 16 * N);
    }
#pragma unroll
    for (int kk = 0; kk < 16; kk++) {
      float4 av = *(const float4*)&As[p][kk][ty * 4];
      float4 bv = *(const float4*)&Bs[p][kk][tx * 4];
      float a[4] = {av.x, av.y, av.z, av.w};
      float b[4] = {bv.x, bv.y, bv.z, bv.w};
#pragma unroll
      for (int i = 0; i < 4; i++)
#pragma unroll
        for (int j = 0; j < 4; j++) accb[i][j] = fmaf(a[i], b[j], accb[i][j]);
    }
    if (((((t + 1) << 4) % 384) == 0) || (t + 1 == nk)) {
#pragma unroll
      for (int i = 0; i < 4; i++)
#pragma unroll
        for (int j = 0; j < 4; j++) { acc[i][j] += accb[i][j]; accb[i][j] = 0.f; }
    }
    if (t + 1 < nk) {
      const int q = p ^ 1;
      As[q][ak + 0][ar] = aR.x; As[q][ak + 1][ar] = aR.y;
      As[q][ak + 2][ar] = aR.z; As[q][ak + 3][ar] = aR.w;
      *(float4*)&Bs[q][br][bn] = bR;
    }
  }
  float4 bb4 = make_float4(0.f, 0.f, 0.f, 0.f);
  if (bias) bb4 = *(const float4*)&bias[n0 + tx * 4];
#pragma unroll
  for (int i = 0; i < 4; i++) {
    float4 o;
    o.x = acc[i][0] + bb4.x;
    o.y = acc[i][1] + bb4.y;
    o.z = acc[i][2] + bb4.z;
    o.w = acc[i][3] + bb4.w;
    if (act == 1) {
      o.x = gelu_np(o.x); o.y = gelu_np(o.y);
      o.z = gelu_np(o.z); o.w = gelu_np(o.w);
    }
    *(float4*)&C[(m0 + ty * 4 + i) * N + n0 + tx * 4] = o;
  }
}

// ---------------- flash-tile attention: 64 queries x 32-key chunks ----------
// r6/r8-validated single-buffered version.
__global__ __launch_bounds__(256) void attn_kernel(
    const float* __restrict__ Q, const float* __restrict__ Kb,
    const float* __restrict__ Vb, float* __restrict__ ctx)
{
  __shared__ float Qs[64][36];
  __shared__ float Ks[32][36];
  __shared__ float Vs[32][36];
  __shared__ float Ps[64][33];
  __shared__ float l_lds[64];
  const int tid = threadIdx.x;
  const int b = blockIdx.x >> 3, h = blockIdx.x & 7;
  const int q0 = blockIdx.y * 64;
  const int base = (b * 512) * 256 + h * 32;
  const float scale = 0.17677669529663687f;  // fl32(1/sqrt(32))

  {
    int i0 = tid * 2;
    int r = i0 >> 3, c = i0 & 7;
    *(float4*)&Qs[r][c * 4] = *(const float4*)(Q + base + (q0 + r) * 256 + c * 4);
    int i1 = i0 + 1;
    r = i1 >> 3; c = i1 & 7;
    *(float4*)&Qs[r][c * 4] = *(const float4*)(Q + base + (q0 + r) * 256 + c * 4);
  }
  if (tid < 64) l_lds[tid] = 0.f;

  const int tx = tid & 15, ty = tid >> 4;
  const int tx2 = tid & 7, ty2 = tid >> 3;
  float acc[2][4] = {};

  for (int kc = 0; kc < 16; kc++) {
    __syncthreads();
    {
      int r = tid >> 3, c = tid & 7;
      int tok = kc * 32 + r;
      *(float4*)&Ks[r][c * 4] = *(const float4*)(Kb + base + tok * 256 + c * 4);
      *(float4*)&Vs[r][c * 4] = *(const float4*)(Vb + base + tok * 256 + c * 4);
    }
    __syncthreads();
    float s0[4] = {}, s1[4] = {};
#pragma unroll
    for (int d = 0; d < 32; d += 4) {
      float4 k0 = *(const float4*)&Ks[tx][d];
      float4 k1 = *(const float4*)&Ks[tx + 16][d];
#pragma unroll
      for (int i = 0; i < 4; i++) {
        float4 qv = *(const float4*)&Qs[ty * 4 + i][d];
        s0[i] = fmaf(qv.w, k0.w, fmaf(qv.z, k0.z, fmaf(qv.y, k0.y, fmaf(qv.x, k0.x, s0[i]))));
        s1[i] = fmaf(qv.w, k1.w, fmaf(qv.z, k1.z, fmaf(qv.y, k1.y, fmaf(qv.x, k1.x, s1[i]))));
      }
    }
    float rs[4];
#pragma unroll
    for (int i = 0; i < 4; i++) {
      float p0 = expf(s0[i] * scale);
      float p1 = expf(s1[i] * scale);
      Ps[ty * 4 + i][tx] = p0;
      Ps[ty * 4 + i][tx + 16] = p1;
      rs[i] = p0 + p1;
    }
#pragma unroll
    for (int off = 1; off < 16; off <<= 1)
#pragma unroll
      for (int i = 0; i < 4; i++) rs[i] += __shfl_xor(rs[i], off);
    if (tx == 0) {
#pragma unroll
      for (int i = 0; i < 4; i++) l_lds[ty * 4 + i] += rs[i];
    }
    __syncthreads();
#pragma unroll 4
    for (int k = 0; k < 32; k++) {
      float4 vv = *(const float4*)&Vs[k][tx2 * 4];
      float pa = Ps[ty2 * 2][k];
      float pb = Ps[ty2 * 2 + 1][k];
      acc[0][0] = fmaf(pa, vv.x, acc[0][0]);
      acc[0][1] = fmaf(pa, vv.y, acc[0][1]);
      acc[0][2] = fmaf(pa, vv.z, acc[0][2]);
      acc[0][3] = fmaf(pa, vv.w, acc[0][3]);
      acc[1][0] = fmaf(pb, vv.x, acc[1][0]);
      acc[1][1] = fmaf(pb, vv.y, acc[1][1]);
      acc[1][2] = fmaf(pb, vv.z, acc[1][2]);
      acc[1][3] = fmaf(pb, vv.w, acc[1][3]);
    }
  }
  __syncthreads();
#pragma unroll
  for (int i = 0; i < 2; i++) {
    float inv = 1.f / l_lds[ty2 * 2 + i];
    float4 o;
    o.x = acc[i][0] * inv; o.y = acc[i][1] * inv;
    o.z = acc[i][2] * inv; o.w = acc[i][3] * inv;
    *(float4*)(ctx + base + (q0 + ty2 * 2 + i) * 256 + tx2 * 4) = o;
  }
}

// ---------------- fused residual + LayerNorm (+ optional Atok) --------------
// r8-validated: 4 rows/block, grid 2048.
__global__ __launch_bounds__(256) void ln_kernel(
    const float* __restrict__ X, const float* __restrict__ R,
    const float* __restrict__ g, const float* __restrict__ bt,
    float* __restrict__ Y, int hasR, float* __restrict__ Atok)
{
  __shared__ float rows[4][256];
  const int w = threadIdx.x >> 6, lane = threadIdx.x & 63;
  const int row = blockIdx.x * 4 + w;
  float4 xv = *(const float4*)(X + row * 256 + lane * 4);
  if (hasR) {
    float4 rv = *(const float4*)(R + row * 256 + lane * 4);
    xv.x += rv.x; xv.y += rv.y; xv.z += rv.z; xv.w += rv.w;
  }
  *(float4*)&rows[w][lane * 4] = xv;
  __syncthreads();
  float sum = np_pairwise256(rows[w], lane);
  float mean = sum * (1.0f / 256.0f);
  float dx = xv.x - mean, dy = xv.y - mean, dz = xv.z - mean, dw = xv.w - mean;
  __syncthreads();
  float4 sq; sq.x = dx * dx; sq.y = dy * dy; sq.z = dz * dz; sq.w = dw * dw;
  *(float4*)&rows[w][lane * 4] = sq;
  __syncthreads();
  float vsum = np_pairwise256(rows[w], lane);
  float var = vsum * (1.0f / 256.0f);
  float inv = 1.0f / sqrtf(var + 1e-5f);
  float4 gv = *(const float4*)(g + lane * 4);
  float4 bv = *(const float4*)(bt + lane * 4);
  float4 o;
  o.x = ((dx * inv) * gv.x) + bv.x;
  o.y = ((dy * inv) * gv.y) + bv.y;
  o.z = ((dz * inv) * gv.z) + bv.z;
  o.w = ((dw * inv) * gv.w) + bv.w;
  *(float4*)(Y + row * 256 + lane * 4) = o;
  if (Atok) {
    float4 s2; s2.x = o.x * o.x; s2.y = o.y * o.y;
    s2.z = o.z * o.z; s2.w = o.w * o.w;
    __syncthreads();
    *(float4*)&rows[w][lane * 4] = s2;
    __syncthreads();
    float asum = np_pairwise256(rows[w], lane);
    if (lane == 0) Atok[row] = asum;
  }
}

// ---------------- VQ pass 1: 128 tok x 256 codes/block, 8x8 micro -----------
// grid (64,32) = 2048 blocks (r9-validated: occ 29.5%, VALUBusy 75%, 400us).
__global__ __launch_bounds__(256) void vq_partial_kernel(
    const float* __restrict__ H, const float* __restrict__ CB,
    const float* __restrict__ Atok, float* __restrict__ partV,
    int* __restrict__ partI)
{
  __shared__ float As[16][132];
  __shared__ float Bs[16][132];
  const int tid = threadIdx.x;
  const int tx = tid & 15, ty = tid >> 4;
  const int m0 = blockIdx.x * 128;
  const int cg0 = blockIdx.y * 256;
  const int ar = tid >> 1;
  const int ak = (tid & 1) * 8;
  float At[8];
#pragma unroll
  for (int i = 0; i < 8; i++) At[i] = Atok[m0 + ty * 8 + i];
  float bestV[8];
  int bestI[8];
#pragma unroll
  for (int i = 0; i < 8; i++) { bestV[i] = FLT_MAX; bestI[i] = 0; }

  for (int ct = 0; ct < 2; ct++) {
    const int c0 = cg0 + ct * 128;
    float acc[8][8] = {};
    const float* Ap = H + (m0 + ar) * 256 + ak;
    const float* Bp = CB + (c0 + ar) * 256 + ak;
    for (int k0 = 0; k0 < 256; k0 += 16) {
      float4 a0 = *(const float4*)(Ap);
      float4 a1 = *(const float4*)(Ap + 4);
      float4 c0v = *(const float4*)(Bp);
      float4 c1v = *(const float4*)(Bp + 4);
      As[ak + 0][ar] = a0.x; As[ak + 1][ar] = a0.y;
      As[ak + 2][ar] = a0.z; As[ak + 3][ar] = a0.w;
      As[ak + 4][ar] = a1.x; As[ak + 5][ar] = a1.y;
      As[ak + 6][ar] = a1.z; As[ak + 7][ar] = a1.w;
      Bs[ak + 0][ar] = c0v.x; Bs[ak + 1][ar] = c0v.y;
      Bs[ak + 2][ar] = c0v.z; Bs[ak + 3][ar] = c0v.w;
      Bs[ak + 4][ar] = c1v.x; Bs[ak + 5][ar] = c1v.y;
      Bs[ak + 6][ar] = c1v.z; Bs[ak + 7][ar] = c1v.w;
      __syncthreads();
#pragma unroll
      for (int kk = 0; kk < 16; kk++) {
        float4 av0 = *(const float4*)&As[kk][ty * 8];
        float4 av1 = *(const float4*)&As[kk][ty * 8 + 4];
        float4 bv0 = *(const float4*)&Bs[kk][tx * 4];       // 2-way: free
        float4 bv1 = *(const float4*)&Bs[kk][64 + tx * 4];  // 2-way: free
        float a[8] = {av0.x, av0.y, av0.z, av0.w, av1.x, av1.y, av1.z, av1.w};
        float b[8] = {bv0.x, bv0.y, bv0.z, bv0.w, bv1.x, bv1.y, bv1.z, bv1.w};
#pragma unroll
        for (int i = 0; i < 8; i++)
#pragma unroll
          for (int j = 0; j < 8; j++) acc[i][j] = fmaf(a[i], b[j], acc[i][j]);
      }
      __syncthreads();
      Ap += 16;
      Bp += 16;
    }
#pragma unroll
    for (int i = 0; i < 8; i++) {
#pragma unroll
      for (int j = 0; j < 8; j++) {
        int code = c0 + ((j < 4) ? (tx * 4 + j) : (64 + tx * 4 + (j - 4)));
        float v = At[i] - 2.0f * acc[i][j];  // fl(A - 2*acc), single rounding
        if (v < bestV[i]) { bestV[i] = v; bestI[i] = code; }
      }
    }
  }
#pragma unroll
  for (int i = 0; i < 8; i++) {
    float v = bestV[i];
    int ii = bestI[i];
#pragma unroll
    for (int off = 1; off < 16; off <<= 1) {
      float ov = __shfl_xor(v, off);
      int oi = __shfl_xor(ii, off);
      if (ov < v || (ov == v && oi < ii)) { v = ov; ii = oi; }
    }
    if (tx == 0) {
      int token = m0 + ty * 8 + i;
      partV[token * 32 + blockIdx.y] = v;
      partI[token * 32 + blockIdx.y] = ii;
    }
  }
}

// ---------------- VQ pass 2: final argmin (32 partials), gather, loss -------
__global__ __launch_bounds__(256) void vq_final_kernel(
    const float* __restrict__ partV, const int* __restrict__ partI,
    const float* __restrict__ HN, const float* __restrict__ CB,
    float* __restrict__ outQuant, float* __restrict__ outIdxF,
    int* __restrict__ idxInt, int* __restrict__ counts,
    float* __restrict__ lossAcc)
{
  const int w = threadIdx.x >> 6, lane = threadIdx.x & 63;
  const int t = blockIdx.x * 4 + w;
  float v = (lane < 32) ? partV[t * 32 + lane] : FLT_MAX;
  int i = (lane < 32) ? partI[t * 32 + lane] : 0x7fffffff;
#pragma unroll
  for (int off = 16; off; off >>= 1) {
    float ov = __shfl_xor(v, off);
    int oi = __shfl_xor(i, off);
    if (ov < v || (ov == v && oi < i)) { v = ov; i = oi; }
  }
  int idx = __shfl(i, 0);
  const float* c = CB + idx * 256;
  const float* hh = HN + t * 256;
  float4 cv = *(const float4*)(c + lane * 4);
  float4 hv = *(const float4*)(hh + lane * 4);
  *(float4*)(outQuant + t * 256 + lane * 4) = cv;
  float ex = cv.x - hv.x, ey = cv.y - hv.y, ez = cv.z - hv.z, ew = cv.w - hv.w;
  float se = ex * ex + ey * ey + ez * ez + ew * ew;
#pragma unroll
  for (int off = 32; off; off >>= 1) se += __shfl_xor(se, off);
  if (lane == 0) {
    outIdxF[t] = (float)idx;
    idxInt[t] = idx;
    atomicAdd(&counts[idx], 1);
    atomicAdd(lossAcc, se);
  }
}

// ---------------- VQ stats: loss finalize + perplexity ----------------------
__global__ __launch_bounds__(256) void vq_stats_kernel(
    const int* __restrict__ counts, const float* __restrict__ lossAcc,
    float* __restrict__ out)
{
  float ent = 0.f;
  for (int k = threadIdx.x; k < 8192; k += 256) {
    float p = (float)counts[k] * (1.0f / 8192.0f);
    ent += p * logf(p + 1e-10f);
  }
#pragma unroll
  for (int off = 32; off; off >>= 1) ent += __shfl_xor(ent, off);
  __shared__ float ws4[4];
  const int w = threadIdx.x >> 6, lane = threadIdx.x & 63;
  if (lane == 0) ws4[w] = ent;
  __syncthreads();
  if (threadIdx.x == 0) {
    float e = ws4[0] + ws4[1] + ws4[2] + ws4[3];
    out[2097152] = 1.25f * lossAcc[0] * (1.0f / 2097152.0f);
    out[2097153] = expf(-e);
  }
}

__global__ void zero_kernel(int* __restrict__ counts, float* __restrict__ lossAcc) {
  int i = blockIdx.x * 256 + threadIdx.x;
  if (i < 8192) counts[i] = 0;
  if (i == 0) lossAcc[0] = 0.f;
}

extern "C" void kernel_launch(void* const* d_in, const int* in_sizes, int n_in,
                              void* d_out, int out_size, void* d_ws, size_t ws_size,
                              hipStream_t stream) {
  const float* x = (const float*)d_in[0];
  const float* w_in = (const float*)d_in[1];
  const float* b_in = (const float*)d_in[2];
  const float* wq = (const float*)d_in[3];
  const float* bq = (const float*)d_in[4];
  const float* wk = (const float*)d_in[5];
  const float* bk = (const float*)d_in[6];
  const float* wv = (const float*)d_in[7];
  const float* bv = (const float*)d_in[8];
  const float* wo = (const float*)d_in[9];
  const float* bo = (const float*)d_in[10];
  const float* ln1g = (const float*)d_in[11];
  const float* ln1b = (const float*)d_in[12];
  const float* ln2g = (const float*)d_in[13];
  const float* ln2b = (const float*)d_in[14];
  const float* ff1w = (const float*)d_in[15];
  const float* ff1b = (const float*)d_in[16];
  const float* ff2w = (const float*)d_in[17];
  const float* ff2b = (const float*)d_in[18];
  const float* preg = (const float*)d_in[19];
  const float* preb = (const float*)d_in[20];
  const float* cb = (const float*)d_in[21];
  float* out = (float*)d_out;

  if (ws_size < (51ull << 20)) return;
  char* ws = (char*)d_ws;
  float* h = (float*)(ws + 0);                  // 0-8MB, live whole transformer
  float* Qb = (float*)(ws + (8ull << 20));      // 8-16MB: Qb -> Ob -> F2 -> HN
  float* Kb2 = (float*)(ws + (16ull << 20));    // 16-24MB (dead after attn)
  float* Vb = (float*)(ws + (24ull << 20));     // 24-32MB (dead after attn)
  float* Cx = (float*)(ws + (32ull << 20));     // 32-40MB (dead after outproj)
  float* Ob = Qb;
  float* F1 = Kb2;                              // 16-48MB [8192,1024]
  float* F2 = Qb;
  float* HN = Qb;
  // smalls at 48MB+ (~50.7MB end, under the 51MB floor)
  char* smallbase = ws + (48ull << 20);
  float* Atok = (float*)(smallbase);                                   // 32KB
  float* partV = (float*)(smallbase + (512ull << 10));                 // 1MB
  int* partI = (int*)(smallbase + (512ull << 10) + (1ull << 20));      // 1MB
  int* idxInt = (int*)(smallbase + (512ull << 10) + (2ull << 20));     // 32KB
  int* counts = (int*)(smallbase + (512ull << 10) + (2ull << 20) + (64ull << 10));
  float* lossAcc = (float*)(smallbase + (512ull << 10) + (2ull << 20) + (128ull << 10));

  // h = x @ w_in + b_in   [8192,512]x[512,256]
  gemm64_kernel<<<dim3(128, 4), 256, 0, stream>>>(x, w_in, b_in, h, NTOK, 256, 512, 0);

  for (int i = 0; i < 3; i++) {
    qkv_kernel<<<dim3(64, 6), 256, 0, stream>>>(
        h, wq + i * 65536, bq + i * 256, wk + i * 65536, bk + i * 256,
        wv + i * 65536, bv + i * 256, Qb, Kb2, Vb);
    attn_kernel<<<dim3(128, 8), 256, 0, stream>>>(Qb, Kb2, Vb, Cx);
    gemm64_kernel<<<dim3(128, 4), 256, 0, stream>>>(Cx, wo + i * 65536, bo + i * 256, Ob, NTOK, 256, 256, 0);
    ln_kernel<<<2048, 256, 0, stream>>>(h, Ob, ln1g + i * 256, ln1b + i * 256, h, 1, nullptr);
    gemm128_kernel<<<dim3(64, 8), 256, 0, stream>>>(h, ff1w + i * 262144, ff1b + i * 1024, F1, 1024, 256, 1);
    gemm64_kernel<<<dim3(128, 4), 256, 0, stream>>>(F1, ff2w + i * 262144, ff2b + i * 256, F2, NTOK, 256, 1024, 0);
    ln_kernel<<<2048, 256, 0, stream>>>(h, F2, ln2g + i * 256, ln2b + i * 256, h, 1, nullptr);
  }
  ln_kernel<<<2048, 256, 0, stream>>>(h, nullptr, preg, preb, HN, 0, Atok);

  zero_kernel<<<32, 256, 0, stream>>>(counts, lossAcc);
  vq_partial_kernel<<<dim3(64, 32), 256, 0, stream>>>(HN, cb, Atok, partV, partI);
  vq_final_kernel<<<2048, 256, 0, stream>>>(partV, partI, HN, cb,
                                            out, out + 2097154, idxInt, counts, lossAcc);
  vq_stats_kernel<<<1, 256, 0, stream>>>(counts, lossAcc, out);
}